// Round 16
// baseline (78.320 us; speedup 1.0000x reference)
//
#include <hip/hip_runtime.h>
#include <math.h>

#define NB   32
#define CCH  64
#define HWD  1024
#define CHW  65536     // C*H*W per sample
#define EPSV 1e-5f

typedef __attribute__((ext_vector_type(8))) short bf16x8;
typedef __attribute__((ext_vector_type(4))) float f32x4;

__device__ __forceinline__ unsigned f2b(float x) {
    union { float f; unsigned u; } v; v.f = x;
    return (v.u + 0x7fffu + ((v.u >> 16) & 1u)) >> 16;   // RNE bf16 bits
}
__device__ __forceinline__ float b2f(unsigned short u) {
    union { unsigned u; float f; } v; v.u = ((unsigned)u) << 16;
    return v.f;
}

// ---------------------------------------------------------------------------
// Kernel 1: partial LN stats. grid (chunk=8, which=3, n=32), block 256.
// ---------------------------------------------------------------------------
__global__ __launch_bounds__(256)
void k_stats(const float* __restrict__ q, const float* __restrict__ k,
             const float* __restrict__ v, float* __restrict__ part)
{
    const int chunk = blockIdx.x, which = blockIdx.y, n = blockIdx.z;
    const float* x = (which == 0) ? q : (which == 1 ? k : v);
    const float4* x4 = (const float4*)(x + (size_t)n * CHW) + chunk * 2048;
    float s = 0.f, ss = 0.f;
#pragma unroll
    for (int i = 0; i < 8; ++i) {
        float4 t = x4[threadIdx.x + i * 256];
        s  += t.x + t.y + t.z + t.w;
        ss += t.x * t.x + t.y * t.y + t.z * t.z + t.w * t.w;
    }
    __shared__ float rs[256], rss[256];
    rs[threadIdx.x] = s; rss[threadIdx.x] = ss;
    __syncthreads();
    for (int off = 128; off > 0; off >>= 1) {
        if (threadIdx.x < off) {
            rs[threadIdx.x]  += rs[threadIdx.x + off];
            rss[threadIdx.x] += rss[threadIdx.x + off];
        }
        __syncthreads();
    }
    if (threadIdx.x == 0) {
        const int b = (n * 3 + which) * 8 + chunk;
        part[b * 2 + 0] = rs[0];
        part[b * 2 + 1] = rss[0];
    }
}

// ---------------------------------------------------------------------------
// Kernel 2 (MFMA): LN + 1x1-conv projections. grid (pt=16, n=32), block 256.
// Unchanged from R15 (passing, ~9us).
// ---------------------------------------------------------------------------
__global__ __launch_bounds__(256, 4)
void k_proj(const float* __restrict__ q,  const float* __restrict__ k,  const float* __restrict__ v,
            const float* __restrict__ w1, const float* __restrict__ b1,
            const float* __restrict__ w2, const float* __restrict__ b2,
            const float* __restrict__ w3, const float* __restrict__ b3,
            const float* __restrict__ wq, const float* __restrict__ bq,
            const float* __restrict__ wk, const float* __restrict__ bk,
            const float* __restrict__ wv, const float* __restrict__ bv,
            const float* __restrict__ part,
            float* __restrict__ qn, short* __restrict__ pqt,
            short* __restrict__ pkt, short* __restrict__ pvb)
{
    __shared__ short xnb[64][72];      // bf16 LN output, [pixel][channel]
    __shared__ float musd[6];
    const int pt = blockIdx.x, n = blockIdx.y;
    const int t = threadIdx.x;
    const int w = t >> 6, l = t & 63;
    const int l15 = l & 15, lg = l >> 4;

    if (t < 3) {
        float s = 0.f, ss = 0.f;
#pragma unroll
        for (int cidx = 0; cidx < 8; ++cidx) {
            const int b = (n * 3 + t) * 8 + cidx;
            s  += part[b * 2 + 0];
            ss += part[b * 2 + 1];
        }
        const float mu = s * (1.0f / CHW);
        musd[t * 2 + 0] = mu;
        musd[t * 2 + 1] = rsqrtf(ss * (1.0f / CHW) - mu * mu + EPSV);
    }
    __syncthreads();

    const float* src[3]   = {q, k, v};
    const float* lw[3]    = {w1, w2, w3};
    const float* lb[3]    = {b1, b2, b3};
    const float* pw[3]    = {wq, wk, wv};
    const float* pbias[3] = {bq, bk, bv};

    for (int tt = 0; tt < 3; ++tt) {
        const float sc = (tt == 0) ? 0.125f : 1.0f;     // fold 1/sqrt(C) into W,b

        bf16x8 whi[2], wlo[2];
#pragma unroll
        for (int ks = 0; ks < 2; ++ks) {
            float wf[8];
            *(float4*)&wf[0] = *(const float4*)&pw[tt][(w * 16 + l15) * 64 + ks * 32 + lg * 8];
            *(float4*)&wf[4] = *(const float4*)&pw[tt][(w * 16 + l15) * 64 + ks * 32 + lg * 8 + 4];
#pragma unroll
            for (int e = 0; e < 8; ++e) {
                const float ws = wf[e] * sc;
                const unsigned hi = f2b(ws);
                whi[ks][e] = (short)hi;
                wlo[ks][e] = (short)f2b(ws - b2f((unsigned short)hi));
            }
        }

        const float mu = musd[tt * 2], is = musd[tt * 2 + 1];
        for (int idx = t; idx < 1024; idx += 256) {
            const int c = idx >> 4, p4 = idx & 15;
            const int gi = c * HWD + pt * 64 + p4 * 4;
            float4 xv = *(const float4*)&src[tt][(size_t)n * CHW + gi];
            float4 w4 = *(const float4*)&lw[tt][gi];
            float4 b4 = *(const float4*)&lb[tt][gi];
            float4 r;
            r.x = (xv.x - mu) * is * w4.x + b4.x;
            r.y = (xv.y - mu) * is * w4.y + b4.y;
            r.z = (xv.z - mu) * is * w4.z + b4.z;
            r.w = (xv.w - mu) * is * w4.w + b4.w;
            if (tt == 0) *(float4*)&qn[(size_t)n * CHW + gi] = r;
            xnb[p4 * 4 + 0][c] = (short)f2b(r.x);
            xnb[p4 * 4 + 1][c] = (short)f2b(r.y);
            xnb[p4 * 4 + 2][c] = (short)f2b(r.z);
            xnb[p4 * 4 + 3][c] = (short)f2b(r.w);
        }
        __syncthreads();

        if (tt < 2) {
            const float4 bb = *(const float4*)&pbias[tt][w * 16 + lg * 4];
            short* dst = (tt == 0) ? pqt : pkt;
#pragma unroll
            for (int pt4 = 0; pt4 < 4; ++pt4) {
                f32x4 acc = {};
#pragma unroll
                for (int ks = 0; ks < 2; ++ks) {
                    bf16x8 xb = *(const bf16x8*)&xnb[pt4 * 16 + l15][ks * 32 + lg * 8];
                    acc = __builtin_amdgcn_mfma_f32_16x16x32_bf16(whi[ks], xb, acc, 0, 0, 0);
                    acc = __builtin_amdgcn_mfma_f32_16x16x32_bf16(wlo[ks], xb, acc, 0, 0, 0);
                }
                const int pix = pt * 64 + pt4 * 16 + l15;
                uint2 u;
                u.x = (f2b(acc[1] + bb.y * sc) << 16) | f2b(acc[0] + bb.x * sc);
                u.y = (f2b(acc[3] + bb.w * sc) << 16) | f2b(acc[2] + bb.z * sc);
                *(uint2*)&dst[(size_t)n * CHW + pix * 64 + w * 16 + lg * 4] = u;
            }
        } else {
            const float bo = pbias[2][w * 16 + l15];
#pragma unroll
            for (int pt4 = 0; pt4 < 4; ++pt4) {
                f32x4 acc = {};
#pragma unroll
                for (int ks = 0; ks < 2; ++ks) {
                    bf16x8 xb = *(const bf16x8*)&xnb[pt4 * 16 + l15][ks * 32 + lg * 8];
                    acc = __builtin_amdgcn_mfma_f32_16x16x32_bf16(xb, whi[ks], acc, 0, 0, 0);
                    acc = __builtin_amdgcn_mfma_f32_16x16x32_bf16(xb, wlo[ks], acc, 0, 0, 0);
                }
                const int o   = w * 16 + l15;
                const int px4 = pt * 64 + pt4 * 16 + lg * 4;
                uint2 u;
                u.x = (f2b(acc[1] + bo) << 16) | f2b(acc[0] + bo);
                u.y = (f2b(acc[3] + bo) << 16) | f2b(acc[2] + bo);
                *(uint2*)&pvb[(size_t)n * CHW + o * HWD + px4] = u;
            }
        }
        __syncthreads();
    }
}

// ---------------------------------------------------------------------------
// Kernel 3 (64-col tile, 16 waves): R14 counters showed 4 serial blocks/CU
// with ~75% all-pipe-idle per block (fixed per-block stall tax). Merge jb
// pairs: grid 512, 1024 threads, 1 block/CU (LDS 145KB) -> 2 serial blocks/CU
// (was 4), same 16 resident waves/CU. Per-wave work shape identical to R15
// (wave = (i-slab, j-half), acc[8][2], 8-partial merge in same order ->
// bitwise-same P). Phase 4: 8 PV waves (4 c-tiles x 2 j-halves) + 8 writer
// waves, each owning 128 i-rows x all 64 cols (full 256B per row).
// ---------------------------------------------------------------------------
__global__ __launch_bounds__(1024, 1)
void k_attn4(const short* __restrict__ pqt, const short* __restrict__ pkt,
             const short* __restrict__ pvb, const float* __restrict__ qn,
             float* __restrict__ xout, float* __restrict__ attn)
{
    __shared__ __align__(16) char smem[131072 + 9216 + 8192];
    short* q_lds = (short*)(smem + 131072);
    float* wredM = (float*)(smem + 131072 + 9216);  // [16][64] per-wave max
    float* wredS = wredM + 1024;                    // [16][64] per-wave sum

    // XCD swizzle: 512 wgs = 8 XCDs x 64; 4 consecutive samples/XCD
    const int wg  = blockIdx.x;
    const int xcd = wg & 7, lid = wg >> 3;
    const int n   = xcd * 4 + (lid >> 4);
    const int jb  = lid & 15;                 // 64-col tile index
    const size_t nb = (size_t)n * CHW;
    const int t = threadIdx.x;
    const int w = t >> 6;                     // wave 0..15
    const int l = t & 63;
    const int l15 = l & 15, lg = l >> 4;
    const int jh    = w & 1;                  // j-half (32 cols)
    const int islab = w >> 1;                 // i-slab (128 rows)
    const int ibase = islab * 128;

    // ---- stage Q^T tile: q_lds[j][c], 64 j x 64 c (first 512 threads)
    if (t < 512) {
        const int j = t >> 3, c8 = (t & 7) * 8;
        *(bf16x8*)&q_lds[j * 72 + c8] =
            *(const bf16x8*)&pqt[nb + (size_t)(jb * 64 + j) * 64 + c8];
    }
    __syncthreads();

    // ---- phase 1: S = K^T Q  (wave: 128 i-rows x its 32-col half)
    f32x4 acc[8][2] = {};
#pragma unroll
    for (int ks = 0; ks < 2; ++ks) {
        bf16x8 bqf[2];
#pragma unroll
        for (int jt = 0; jt < 2; ++jt)
            bqf[jt] = *(const bf16x8*)&q_lds[(jh * 32 + jt * 16 + l15) * 72 + ks * 32 + lg * 8];
#pragma unroll
        for (int f = 0; f < 8; ++f) {
            const int i = ibase + f * 16 + l15;
            bf16x8 af = *(const bf16x8*)&pkt[nb + (size_t)i * 64 + ks * 32 + lg * 8];
#pragma unroll
            for (int jt = 0; jt < 2; ++jt)
                acc[f][jt] = __builtin_amdgcn_mfma_f32_16x16x32_bf16(
                    af, bqf[jt], acc[f][jt], 0, 0, 0);
        }
    }

    // ---- phase 2: per-wave softmax partials (max + exp + sum), 1 barrier
    float mself[2];
#pragma unroll
    for (int jt = 0; jt < 2; ++jt) {
        float m = -1e30f;
#pragma unroll
        for (int f = 0; f < 8; ++f)
#pragma unroll
            for (int r = 0; r < 4; ++r) m = fmaxf(m, acc[f][jt][r]);
        m = fmaxf(m, __shfl_xor(m, 16));
        m = fmaxf(m, __shfl_xor(m, 32));
        mself[jt] = m;
        float s = 0.f;
#pragma unroll
        for (int f = 0; f < 8; ++f)
#pragma unroll
            for (int r = 0; r < 4; ++r) {
                float e = __expf(acc[f][jt][r] - m);
                acc[f][jt][r] = e;
                s += e;
            }
        s += __shfl_xor(s, 16);
        s += __shfl_xor(s, 32);
        if (l < 16) {
            wredM[w * 64 + jh * 32 + jt * 16 + l] = m;
            wredS[w * 64 + jh * 32 + jt * 16 + l] = s;
        }
    }
    __syncthreads();

    // ---- phase 3: merge 8 i-slab partials per column; P (bf16) -> LDS
#pragma unroll
    for (int jt = 0; jt < 2; ++jt) {
        const int jgl = jh * 32 + jt * 16 + l15;
        float M = wredM[jh * 64 + jgl];
#pragma unroll
        for (int s8 = 1; s8 < 8; ++s8)
            M = fmaxf(M, wredM[(2 * s8 + jh) * 64 + jgl]);
        float S = 0.f;
#pragma unroll
        for (int s8 = 0; s8 < 8; ++s8)
            S += wredS[(2 * s8 + jh) * 64 + jgl] * __expf(wredM[(2 * s8 + jh) * 64 + jgl] - M);
        const float fac = __expf(mself[jt] - M) / S;
#pragma unroll
        for (int f = 0; f < 8; ++f) {
            const int i0 = ibase + f * 16 + lg * 4;
            uint2 pw;
            pw.x = (f2b(acc[f][jt][1] * fac) << 16) | f2b(acc[f][jt][0] * fac);
            pw.y = (f2b(acc[f][jt][3] * fac) << 16) | f2b(acc[f][jt][2] * fac);
            const unsigned byte = (unsigned)jgl * 2048u + (((unsigned)i0 * 2u) ^ (((unsigned)jgl & 7u) << 4));
            *(uint2*)(smem + byte) = pw;
        }
    }
    __syncthreads();

    // ---- phase 4 (role split): 8 PV waves + 8 attn-writer waves
    if (w < 8) {
        // PV: wave = (c-tile cm, j-half jh2); full K=1024 contraction.
        const int cm = w & 3, jh2 = w >> 2;
        f32x4 oacc[2] = {};
        __builtin_amdgcn_s_setprio(1);
#pragma unroll 4
        for (int ks = 0; ks < 32; ++ks) {
            bf16x8 av = *(const bf16x8*)&pvb[nb + (size_t)(cm * 16 + l15) * HWD + ks * 32 + lg * 8];
            const unsigned ib = (unsigned)(ks * 32 + lg * 8) * 2u;
#pragma unroll
            for (int u = 0; u < 2; ++u) {
                const int j = jh2 * 32 + u * 16 + l15;
                bf16x8 bp = *(const bf16x8*)(smem + (unsigned)j * 2048u + (ib ^ (((unsigned)j & 7u) << 4)));
                oacc[u] = __builtin_amdgcn_mfma_f32_16x16x32_bf16(av, bp, oacc[u], 0, 0, 0);
            }
        }
        __builtin_amdgcn_s_setprio(0);
#pragma unroll
        for (int u = 0; u < 2; ++u) {
            const int j = jh2 * 32 + u * 16 + l15;
#pragma unroll
            for (int r = 0; r < 4; ++r) {
                const int c = cm * 16 + lg * 4 + r;
                const size_t o = nb + (size_t)c * HWD + jb * 64 + j;
                xout[o] = oacc[u][r] + qn[o];
            }
        }
    } else {
        // attn writer: wave (w-8) owns 128 i-rows x all 64 cols.
        // Per instr: 4 rows x 256B (full sectors). r-rotation de-phases banks.
        float* aout = attn + (size_t)n * HWD * HWD + jb * 64;
        const int ww   = w - 8;
        const int jq   = (l & 15) * 4;
        const int isub = l >> 4;
        const int i00  = ww * 128;
#pragma unroll 4
        for (int g = 0; g < 32; ++g) {
            const int i = i00 + g * 4 + isub;
            f32x4 o4;
#pragma unroll
            for (int rr = 0; rr < 4; ++rr) {
                const int rro = (rr + isub) & 3;
                const unsigned j = (unsigned)(jq + rro);
                const unsigned byte = j * 2048u + (((unsigned)i * 2u) ^ ((j & 7u) << 4));
                o4[rro] = b2f(*(const unsigned short*)(smem + byte));
            }
            *(f32x4*)&aout[(size_t)i * HWD + jq] = o4;
        }
    }
}

// ---------------------------------------------------------------------------
extern "C" void kernel_launch(void* const* d_in, const int* in_sizes, int n_in,
                              void* d_out, int out_size, void* d_ws, size_t ws_size,
                              hipStream_t stream)
{
    const float* q  = (const float*)d_in[0];
    const float* k  = (const float*)d_in[1];
    const float* v  = (const float*)d_in[2];
    const float* w1 = (const float*)d_in[3];
    const float* b1 = (const float*)d_in[4];
    const float* w2 = (const float*)d_in[5];
    const float* b2 = (const float*)d_in[6];
    const float* w3 = (const float*)d_in[7];
    const float* b3 = (const float*)d_in[8];
    const float* wq = (const float*)d_in[9];
    const float* bq = (const float*)d_in[10];
    const float* wk = (const float*)d_in[11];
    const float* bk = (const float*)d_in[12];
    const float* wv = (const float*)d_in[13];
    const float* bv = (const float*)d_in[14];

    // ws layout: part fp32 [1536] @0; qn fp32 @4096; pqt/pkt/pvb bf16 after.
    float* ws   = (float*)d_ws;
    float* part = ws;
    float* qn   = ws + 4096;
    short* pqt  = (short*)(qn + 2097152);
    short* pkt  = pqt + 2097152;
    short* pvb  = pkt + 2097152;

    float* xout = (float*)d_out;            // (N, C*H*W)
    float* attn = xout + 2097152;           // (N, HW, HW)

    k_stats<<<dim3(8, 3, 32), 256, 0, stream>>>(q, k, v, part);
    k_proj<<<dim3(16, 32), 256, 0, stream>>>(q, k, v, w1, b1, w2, b2, w3, b3,
                                             wq, bq, wk, bk, wv, bv,
                                             part, qn, pqt, pkt, pvb);
    k_attn4<<<dim3(512), dim3(1024), 0, stream>>>(pqt, pkt, pvb, qn, xout, attn);
}

// Round 17
// 72.952 us; speedup vs baseline: 1.0736x; 1.0736x over previous
//
#include <hip/hip_runtime.h>
#include <math.h>

#define NB   32
#define CCH  64
#define HWD  1024
#define CHW  65536     // C*H*W per sample
#define EPSV 1e-5f

typedef __attribute__((ext_vector_type(8))) short bf16x8;
typedef __attribute__((ext_vector_type(4))) float f32x4;

__device__ __forceinline__ unsigned f2b(float x) {
    union { float f; unsigned u; } v; v.f = x;
    return (v.u + 0x7fffu + ((v.u >> 16) & 1u)) >> 16;   // RNE bf16 bits
}
__device__ __forceinline__ float b2f(unsigned short u) {
    union { unsigned u; float f; } v; v.u = ((unsigned)u) << 16;
    return v.f;
}

// ---------------------------------------------------------------------------
// Kernel 1: partial LN stats. grid (chunk=8, which=3, n=32), block 256.
// ~4 us, at HBM read floor for 24 MB.
// ---------------------------------------------------------------------------
__global__ __launch_bounds__(256)
void k_stats(const float* __restrict__ q, const float* __restrict__ k,
             const float* __restrict__ v, float* __restrict__ part)
{
    const int chunk = blockIdx.x, which = blockIdx.y, n = blockIdx.z;
    const float* x = (which == 0) ? q : (which == 1 ? k : v);
    const float4* x4 = (const float4*)(x + (size_t)n * CHW) + chunk * 2048;
    float s = 0.f, ss = 0.f;
#pragma unroll
    for (int i = 0; i < 8; ++i) {
        float4 t = x4[threadIdx.x + i * 256];
        s  += t.x + t.y + t.z + t.w;
        ss += t.x * t.x + t.y * t.y + t.z * t.z + t.w * t.w;
    }
    __shared__ float rs[256], rss[256];
    rs[threadIdx.x] = s; rss[threadIdx.x] = ss;
    __syncthreads();
    for (int off = 128; off > 0; off >>= 1) {
        if (threadIdx.x < off) {
            rs[threadIdx.x]  += rs[threadIdx.x + off];
            rss[threadIdx.x] += rss[threadIdx.x + off];
        }
        __syncthreads();
    }
    if (threadIdx.x == 0) {
        const int b = (n * 3 + which) * 8 + chunk;
        part[b * 2 + 0] = rs[0];
        part[b * 2 + 1] = rss[0];
    }
}

// ---------------------------------------------------------------------------
// Kernel 2 (MFMA): LN + 1x1-conv projections. grid (pt=16, n=32), block 256.
// xn staged bf16 [px][72c] in LDS; W fp32 -> hi/lo bf16 split (2 MFMAs).
// Q scale 1/8 folded into W,b. qn residual exact fp32. LDS 9.5 KB.
// ~9 us vs ~7 us traffic floor.
// ---------------------------------------------------------------------------
__global__ __launch_bounds__(256, 4)
void k_proj(const float* __restrict__ q,  const float* __restrict__ k,  const float* __restrict__ v,
            const float* __restrict__ w1, const float* __restrict__ b1,
            const float* __restrict__ w2, const float* __restrict__ b2,
            const float* __restrict__ w3, const float* __restrict__ b3,
            const float* __restrict__ wq, const float* __restrict__ bq,
            const float* __restrict__ wk, const float* __restrict__ bk,
            const float* __restrict__ wv, const float* __restrict__ bv,
            const float* __restrict__ part,
            float* __restrict__ qn, short* __restrict__ pqt,
            short* __restrict__ pkt, short* __restrict__ pvb)
{
    __shared__ short xnb[64][72];      // bf16 LN output, [pixel][channel]
    __shared__ float musd[6];
    const int pt = blockIdx.x, n = blockIdx.y;
    const int t = threadIdx.x;
    const int w = t >> 6, l = t & 63;
    const int l15 = l & 15, lg = l >> 4;

    if (t < 3) {
        float s = 0.f, ss = 0.f;
#pragma unroll
        for (int cidx = 0; cidx < 8; ++cidx) {
            const int b = (n * 3 + t) * 8 + cidx;
            s  += part[b * 2 + 0];
            ss += part[b * 2 + 1];
        }
        const float mu = s * (1.0f / CHW);
        musd[t * 2 + 0] = mu;
        musd[t * 2 + 1] = rsqrtf(ss * (1.0f / CHW) - mu * mu + EPSV);
    }
    __syncthreads();

    const float* src[3]   = {q, k, v};
    const float* lw[3]    = {w1, w2, w3};
    const float* lb[3]    = {b1, b2, b3};
    const float* pw[3]    = {wq, wk, wv};
    const float* pbias[3] = {bq, bk, bv};

    for (int tt = 0; tt < 3; ++tt) {
        const float sc = (tt == 0) ? 0.125f : 1.0f;     // fold 1/sqrt(C) into W,b

        bf16x8 whi[2], wlo[2];
#pragma unroll
        for (int ks = 0; ks < 2; ++ks) {
            float wf[8];
            *(float4*)&wf[0] = *(const float4*)&pw[tt][(w * 16 + l15) * 64 + ks * 32 + lg * 8];
            *(float4*)&wf[4] = *(const float4*)&pw[tt][(w * 16 + l15) * 64 + ks * 32 + lg * 8 + 4];
#pragma unroll
            for (int e = 0; e < 8; ++e) {
                const float ws = wf[e] * sc;
                const unsigned hi = f2b(ws);
                whi[ks][e] = (short)hi;
                wlo[ks][e] = (short)f2b(ws - b2f((unsigned short)hi));
            }
        }

        const float mu = musd[tt * 2], is = musd[tt * 2 + 1];
        for (int idx = t; idx < 1024; idx += 256) {
            const int c = idx >> 4, p4 = idx & 15;
            const int gi = c * HWD + pt * 64 + p4 * 4;
            float4 xv = *(const float4*)&src[tt][(size_t)n * CHW + gi];
            float4 w4 = *(const float4*)&lw[tt][gi];
            float4 b4 = *(const float4*)&lb[tt][gi];
            float4 r;
            r.x = (xv.x - mu) * is * w4.x + b4.x;
            r.y = (xv.y - mu) * is * w4.y + b4.y;
            r.z = (xv.z - mu) * is * w4.z + b4.z;
            r.w = (xv.w - mu) * is * w4.w + b4.w;
            if (tt == 0) *(float4*)&qn[(size_t)n * CHW + gi] = r;
            xnb[p4 * 4 + 0][c] = (short)f2b(r.x);
            xnb[p4 * 4 + 1][c] = (short)f2b(r.y);
            xnb[p4 * 4 + 2][c] = (short)f2b(r.z);
            xnb[p4 * 4 + 3][c] = (short)f2b(r.w);
        }
        __syncthreads();

        if (tt < 2) {
            const float4 bb = *(const float4*)&pbias[tt][w * 16 + lg * 4];
            short* dst = (tt == 0) ? pqt : pkt;
#pragma unroll
            for (int pt4 = 0; pt4 < 4; ++pt4) {
                f32x4 acc = {};
#pragma unroll
                for (int ks = 0; ks < 2; ++ks) {
                    bf16x8 xb = *(const bf16x8*)&xnb[pt4 * 16 + l15][ks * 32 + lg * 8];
                    acc = __builtin_amdgcn_mfma_f32_16x16x32_bf16(whi[ks], xb, acc, 0, 0, 0);
                    acc = __builtin_amdgcn_mfma_f32_16x16x32_bf16(wlo[ks], xb, acc, 0, 0, 0);
                }
                const int pix = pt * 64 + pt4 * 16 + l15;
                uint2 u;
                u.x = (f2b(acc[1] + bb.y * sc) << 16) | f2b(acc[0] + bb.x * sc);
                u.y = (f2b(acc[3] + bb.w * sc) << 16) | f2b(acc[2] + bb.z * sc);
                *(uint2*)&dst[(size_t)n * CHW + pix * 64 + w * 16 + lg * 4] = u;
            }
        } else {
            const float bo = pbias[2][w * 16 + l15];
#pragma unroll
            for (int pt4 = 0; pt4 < 4; ++pt4) {
                f32x4 acc = {};
#pragma unroll
                for (int ks = 0; ks < 2; ++ks) {
                    bf16x8 xb = *(const bf16x8*)&xnb[pt4 * 16 + l15][ks * 32 + lg * 8];
                    acc = __builtin_amdgcn_mfma_f32_16x16x32_bf16(xb, whi[ks], acc, 0, 0, 0);
                    acc = __builtin_amdgcn_mfma_f32_16x16x32_bf16(xb, wlo[ks], acc, 0, 0, 0);
                }
                const int o   = w * 16 + l15;
                const int px4 = pt * 64 + pt4 * 16 + lg * 4;
                uint2 u;
                u.x = (f2b(acc[1] + bo) << 16) | f2b(acc[0] + bo);
                u.y = (f2b(acc[3] + bo) << 16) | f2b(acc[2] + bo);
                *(uint2*)&pvb[(size_t)n * CHW + o * HWD + px4] = u;
            }
        }
        __syncthreads();
    }
}

// ---------------------------------------------------------------------------
// Kernel 3 (final, best-measured = R15): one block per (n, 32-col tile),
// 8 waves, LDS 72 KB -> 2 blocks/CU. Q-LDS stage; QK^T from global K frags;
// 1-barrier per-wave softmax with merged rescale; normalized P (bf16) in
// XOR-swizzled LDS; phase-4 role split: waves 0-3 PV (unique c-tile, 1x V
// traffic) + fused residual xout, waves 4-7 stream attn as full 128B-line
// plain dwordx4 stores. 8 structural alternatives measured 60+/-3 us for
// this kernel (see rounds 4-16); this config is the plateau optimum.
// ---------------------------------------------------------------------------
__global__ __launch_bounds__(512, 4)
void k_attn3(const short* __restrict__ pqt, const short* __restrict__ pkt,
             const short* __restrict__ pvb, const float* __restrict__ qn,
             float* __restrict__ xout, float* __restrict__ attn)
{
    __shared__ __align__(16) char smem[65536 + 4608 + 2048];
    short* q_lds = (short*)(smem + 65536);
    float* wredM = (float*)(smem + 65536 + 4608);   // [8][32] per-wave max
    float* wredS = wredM + 256;                     // [8][32] per-wave sum

    const int wg  = blockIdx.x;
    const int xcd = wg & 7, lid = wg >> 3;
    const int n   = xcd * 4 + (lid >> 5);
    const int jb  = lid & 31;
    const size_t nb = (size_t)n * CHW;
    const int t = threadIdx.x;
    const int w = t >> 6;
    const int l = t & 63;
    const int l15 = l & 15, lg = l >> 4;
    const int ibase = w * 128;

    if (t < 256) {
        const int j = t >> 3, c8 = (t & 7) * 8;
        *(bf16x8*)&q_lds[j * 72 + c8] =
            *(const bf16x8*)&pqt[nb + (size_t)(jb * 32 + j) * 64 + c8];
    }
    __syncthreads();

    // ---- phase 1: S = K^T Q
    f32x4 acc[8][2] = {};
#pragma unroll
    for (int ks = 0; ks < 2; ++ks) {
        bf16x8 bqf[2];
#pragma unroll
        for (int jt = 0; jt < 2; ++jt)
            bqf[jt] = *(const bf16x8*)&q_lds[(jt * 16 + l15) * 72 + ks * 32 + lg * 8];
#pragma unroll
        for (int f = 0; f < 8; ++f) {
            const int i = ibase + f * 16 + l15;
            bf16x8 af = *(const bf16x8*)&pkt[nb + (size_t)i * 64 + ks * 32 + lg * 8];
#pragma unroll
            for (int jt = 0; jt < 2; ++jt)
                acc[f][jt] = __builtin_amdgcn_mfma_f32_16x16x32_bf16(
                    af, bqf[jt], acc[f][jt], 0, 0, 0);
        }
    }

    // ---- phase 2: per-wave softmax, 1 barrier
    float mself[2];
#pragma unroll
    for (int jt = 0; jt < 2; ++jt) {
        float m = -1e30f;
#pragma unroll
        for (int f = 0; f < 8; ++f)
#pragma unroll
            for (int r = 0; r < 4; ++r) m = fmaxf(m, acc[f][jt][r]);
        m = fmaxf(m, __shfl_xor(m, 16));
        m = fmaxf(m, __shfl_xor(m, 32));
        mself[jt] = m;
        float s = 0.f;
#pragma unroll
        for (int f = 0; f < 8; ++f)
#pragma unroll
            for (int r = 0; r < 4; ++r) {
                float e = __expf(acc[f][jt][r] - m);
                acc[f][jt][r] = e;
                s += e;
            }
        s += __shfl_xor(s, 16);
        s += __shfl_xor(s, 32);
        if (l < 16) {
            wredM[w * 32 + jt * 16 + l] = m;
            wredS[w * 32 + jt * 16 + l] = s;
        }
    }
    __syncthreads();

    // ---- phase 3: merge; normalize; P (bf16) -> swizzled LDS
#pragma unroll
    for (int jt = 0; jt < 2; ++jt) {
        const int j = jt * 16 + l15;
        float M = wredM[j];
#pragma unroll
        for (int ww = 1; ww < 8; ++ww) M = fmaxf(M, wredM[ww * 32 + j]);
        float S = 0.f;
#pragma unroll
        for (int ww = 0; ww < 8; ++ww)
            S += wredS[ww * 32 + j] * __expf(wredM[ww * 32 + j] - M);
        const float fac = __expf(mself[jt] - M) / S;
#pragma unroll
        for (int f = 0; f < 8; ++f) {
            const int i0 = ibase + f * 16 + lg * 4;
            uint2 pw;
            pw.x = (f2b(acc[f][jt][1] * fac) << 16) | f2b(acc[f][jt][0] * fac);
            pw.y = (f2b(acc[f][jt][3] * fac) << 16) | f2b(acc[f][jt][2] * fac);
            const unsigned byte = (unsigned)j * 2048u + (((unsigned)i0 * 2u) ^ (((unsigned)j & 7u) << 4));
            *(uint2*)(smem + byte) = pw;
        }
    }
    __syncthreads();

    // ---- phase 4 (role split)
    if (w < 4) {
        f32x4 oacc[2] = {};
        __builtin_amdgcn_s_setprio(1);
#pragma unroll 4
        for (int ks = 0; ks < 32; ++ks) {
            bf16x8 av = *(const bf16x8*)&pvb[nb + (size_t)(w * 16 + l15) * HWD + ks * 32 + lg * 8];
            const unsigned ib = (unsigned)(ks * 32 + lg * 8) * 2u;
#pragma unroll
            for (int u = 0; u < 2; ++u) {
                const int j = u * 16 + l15;
                bf16x8 bp = *(const bf16x8*)(smem + (unsigned)j * 2048u + (ib ^ (((unsigned)j & 7u) << 4)));
                oacc[u] = __builtin_amdgcn_mfma_f32_16x16x32_bf16(av, bp, oacc[u], 0, 0, 0);
            }
        }
        __builtin_amdgcn_s_setprio(0);
#pragma unroll
        for (int u = 0; u < 2; ++u) {
            const int j = u * 16 + l15;
#pragma unroll
            for (int r = 0; r < 4; ++r) {
                const int c = w * 16 + lg * 4 + r;
                const size_t o = nb + (size_t)c * HWD + jb * 32 + j;
                xout[o] = oacc[u][r] + qn[o];
            }
        }
    } else {
        // attn writer: wave (w-4) owns i in [(w-4)*256, +256); full-line
        // dwordx4 stores through L2.
        float* aout = attn + (size_t)n * HWD * HWD + jb * 32;
        const int jq   = (l & 7) * 4;
        const int isub = l >> 3;
        const int i00  = (w - 4) * 256;
#pragma unroll 4
        for (int g = 0; g < 32; ++g) {
            const int i = i00 + g * 8 + isub;
            f32x4 o4;
#pragma unroll
            for (int r = 0; r < 4; ++r) {
                const unsigned j = (unsigned)(jq + r);
                const unsigned byte = j * 2048u + (((unsigned)i * 2u) ^ ((j & 7u) << 4));
                o4[r] = b2f(*(const unsigned short*)(smem + byte));
            }
            *(f32x4*)&aout[(size_t)i * HWD + jq] = o4;
        }
    }
}

// ---------------------------------------------------------------------------
extern "C" void kernel_launch(void* const* d_in, const int* in_sizes, int n_in,
                              void* d_out, int out_size, void* d_ws, size_t ws_size,
                              hipStream_t stream)
{
    const float* q  = (const float*)d_in[0];
    const float* k  = (const float*)d_in[1];
    const float* v  = (const float*)d_in[2];
    const float* w1 = (const float*)d_in[3];
    const float* b1 = (const float*)d_in[4];
    const float* w2 = (const float*)d_in[5];
    const float* b2 = (const float*)d_in[6];
    const float* w3 = (const float*)d_in[7];
    const float* b3 = (const float*)d_in[8];
    const float* wq = (const float*)d_in[9];
    const float* bq = (const float*)d_in[10];
    const float* wk = (const float*)d_in[11];
    const float* bk = (const float*)d_in[12];
    const float* wv = (const float*)d_in[13];
    const float* bv = (const float*)d_in[14];

    // ws layout: part fp32 [1536] @0; qn fp32 @4096; pqt/pkt/pvb bf16 after.
    float* ws   = (float*)d_ws;
    float* part = ws;
    float* qn   = ws + 4096;
    short* pqt  = (short*)(qn + 2097152);
    short* pkt  = pqt + 2097152;
    short* pvb  = pkt + 2097152;

    float* xout = (float*)d_out;            // (N, C*H*W)
    float* attn = xout + 2097152;           // (N, HW, HW)

    k_stats<<<dim3(8, 3, 32), 256, 0, stream>>>(q, k, v, part);
    k_proj<<<dim3(16, 32), 256, 0, stream>>>(q, k, v, w1, b1, w2, b2, w3, b3,
                                             wq, bq, wk, bk, wv, bv,
                                             part, qn, pqt, pkt, pvb);
    k_attn3<<<dim3(1024), dim3(512), 0, stream>>>(pqt, pkt, pvb, qn, xout, attn);
}